// Round 11
// baseline (156.279 us; speedup 1.0000x reference)
//
#include <hip/hip_runtime.h>
#include <math.h>

#define TPB 256
#define PIXPT 4            // pixels per thread in raster phase
#define NSEG_MAX 32
#define MAXBLOCKS 1024
#define MAGIC1 0x13579BDFu
#define MAGIC2 0x2468ACE1u // both != 0xAAAAAAAA workspace poison

// ---------------------------------------------------------------------------
// Order-preserving float->uint map (ascending uint == ascending float).
// ---------------------------------------------------------------------------
__device__ __forceinline__ unsigned int f2ord(float f) {
    unsigned int u = __float_as_uint(f);
    return (u & 0x80000000u) ? ~u : (u | 0x80000000u);
}

// ---------------------------------------------------------------------------
// Two-level poison-safe grid barrier.
//  arrive : one relaxed store per block into its own flag slot (no init).
//  collect: block 0's threads scan the flag array (disjoint addrs, backoff).
//  release: block 0 stores one `go` word; all other blocks poll only that
//           single line with one thread each + s_sleep backoff.
// __threadfence() before arrive (writeback phase writes) and after release
// observed (invalidate stale lines) — same semantics that already verified.
// This kills the 73K-poller contention of the flat barrier (r10: ~40us/bar).
// ---------------------------------------------------------------------------
__device__ __forceinline__ void flag_barrier(unsigned int* flags,
                                             unsigned int* go,
                                             int nblocks, unsigned int magic)
{
    __syncthreads();
    if (threadIdx.x == 0) {
        __threadfence();   // order phase writes before flag store
        __hip_atomic_store(&flags[blockIdx.x], magic,
                           __ATOMIC_RELAXED, __HIP_MEMORY_SCOPE_AGENT);
    }
    if (blockIdx.x == 0) {
        for (int i = threadIdx.x; i < nblocks; i += TPB) {
            while (__hip_atomic_load(&flags[i], __ATOMIC_RELAXED,
                                     __HIP_MEMORY_SCOPE_AGENT) != magic) {
                __builtin_amdgcn_s_sleep(4);
            }
        }
        __syncthreads();
        if (threadIdx.x == 0) {
            __hip_atomic_store(go, magic,
                               __ATOMIC_RELAXED, __HIP_MEMORY_SCOPE_AGENT);
        }
    } else {
        if (threadIdx.x == 0) {
            while (__hip_atomic_load(go, __ATOMIC_RELAXED,
                                     __HIP_MEMORY_SCOPE_AGENT) != magic) {
                __builtin_amdgcn_s_sleep(16);
            }
        }
    }
    __threadfence();       // make other blocks' phase writes visible
    __syncthreads();
}

// ---------------------------------------------------------------------------
// Single fused kernel; 3 phases separated by the grid barrier.
// Phase A: depth keys -> LDS, 8-lane rank per gaussian, lane 0 preprocesses
//          and writes packed params directly to the depth-sorted slot.
// Phase B: (pixel-block, segment) raster -> partial (r,g,b,T).
// Phase C: chain segments far-to-near -> (B,3,H,W).
// params: f4[0]=(mx,my,A,Bc) f4[1]=(D,log2(alpha),r,g) f4[2]=(b,0,0,0),
// A,Bc,D pre-scaled by -0.5*log2(e): alpha_map = exp2(A dx^2+Bc dx dy+D dy^2+l2a)
// ---------------------------------------------------------------------------
extern __shared__ char smem[];

__global__ __launch_bounds__(TPB, 4) void gs_fused(
    const float* __restrict__ pose,
    const float* __restrict__ positions,
    const float* __restrict__ scales,
    const float* __restrict__ rotations,
    const float* __restrict__ opacity,
    const float* __restrict__ features,
    const int* __restrict__ pH,
    const int* __restrict__ pW,
    unsigned int* __restrict__ flagsA,
    unsigned int* __restrict__ goA,
    unsigned int* __restrict__ flagsB,
    unsigned int* __restrict__ goB,
    float* __restrict__ sorted,      // B*N*12
    float* __restrict__ partials,    // nseg*B*HW*4
    float* __restrict__ out,         // B*3*HW
    int N, int B, int HW, int PB, int nseg, int nblocks)
{
    const float C_EXP = -0.72134752044448170f;   // -0.5 * log2(e)
    const int H = *pH;
    const int W = *pW;

    // ---------------- Phase A: prep + rank -> sorted ----------------
    int nprep = (N + 31) >> 5;
    for (int job = blockIdx.x; job < B * nprep; job += nblocks) {
        int b  = job / nprep;
        int cb = job - b * nprep;
        const float* P = pose + b * 16;
        unsigned long long* skey = (unsigned long long*)smem;

        for (int n = threadIdx.x; n < N; n += TPB) {
            float x = positions[n * 3 + 0];
            float y = positions[n * 3 + 1];
            float z = positions[n * 3 + 2];
            float depth = P[8] * x + P[9] * y + P[10] * z + P[11];
            skey[n] = ((unsigned long long)(~f2ord(depth)) << 32) | (unsigned int)n;
        }
        __syncthreads();

        int g = cb * 32 + (threadIdx.x >> 3);
        int s = threadIdx.x & 7;
        if (g < N) {
            unsigned long long kn = skey[g];
            int cnt = 0;
            for (int m = s; m < N; m += 8) cnt += (skey[m] < kn) ? 1 : 0;
            cnt += __shfl_down(cnt, 4, 8);
            cnt += __shfl_down(cnt, 2, 8);
            cnt += __shfl_down(cnt, 1, 8);
            if (s == 0) {
                int rank = cnt;
                float x = positions[g * 3 + 0];
                float y = positions[g * 3 + 1];
                float z = positions[g * 3 + 2];

                float depth = P[8] * x + P[9] * y + P[10] * z + P[11];
                float inv_d = 1.0f / depth;
                float mx = (P[0] * x + P[1] * y + P[2] * z + P[3]) * inv_d;
                float my = (P[4] * x + P[5] * y + P[6] * z + P[7]) * inv_d;

                float qw = rotations[g * 4 + 0];
                float qx = rotations[g * 4 + 1];
                float qy = rotations[g * 4 + 2];
                float qz = rotations[g * 4 + 3];
                float qn = sqrtf(qw * qw + qx * qx + qy * qy + qz * qz);
                qw /= qn; qx /= qn; qy /= qn; qz /= qn;
                float R00 = 1.f - 2.f * (qy * qy + qz * qz);
                float R01 = 2.f * (qx * qy - qw * qz);
                float R02 = 2.f * (qx * qz + qw * qy);
                float R10 = 2.f * (qx * qy + qw * qz);
                float R11 = 1.f - 2.f * (qx * qx + qz * qz);
                float R12 = 2.f * (qy * qz - qw * qx);
                float R20 = 2.f * (qx * qz - qw * qy);
                float R21 = 2.f * (qy * qz + qw * qx);
                float R22 = 1.f - 2.f * (qx * qx + qy * qy);

                float s0 = scales[g * 3 + 0];
                float s1 = scales[g * 3 + 1];
                float s2 = scales[g * 3 + 2];
                float v0 = s0 * s0, v1 = s1 * s1, v2 = s2 * s2;

                float C00 = R00 * R00 * v0 + R01 * R01 * v1 + R02 * R02 * v2;
                float C01 = R00 * R10 * v0 + R01 * R11 * v1 + R02 * R12 * v2;
                float C02 = R00 * R20 * v0 + R01 * R21 * v1 + R02 * R22 * v2;
                float C11 = R10 * R10 * v0 + R11 * R11 * v1 + R12 * R12 * v2;
                float C12 = R10 * R20 * v0 + R11 * R21 * v1 + R12 * R22 * v2;
                float C22 = R20 * R20 * v0 + R21 * R21 * v1 + R22 * R22 * v2;

                // Jacobian uses WORLD z and world x,y (faithful to reference)
                float fx = P[0], fy = P[5];
                float iz = 1.0f / z;
                float a0 = fx * iz;
                float c0 = -fx * x * iz * iz;
                float b1 = fy * iz;
                float c1 = -fy * y * iz * iz;

                float cov00 = a0 * a0 * C00 + 2.f * a0 * c0 * C02 + c0 * c0 * C22;
                float cov01 = a0 * b1 * C01 + a0 * c1 * C02 + c0 * b1 * C12 + c0 * c1 * C22;
                float cov11 = b1 * b1 * C11 + 2.f * b1 * c1 * C12 + c1 * c1 * C22;

                float det = cov00 * cov11 - cov01 * cov01;
                float invdet = 1.0f / det;
                float A  = C_EXP * cov11 * invdet;
                float Bc = C_EXP * -2.0f * cov01 * invdet;
                float D  = C_EXP * cov00 * invdet;
                float l2a = log2f(opacity[g]);

                float4* p4 = (float4*)(sorted + ((size_t)b * N + rank) * 12);
                p4[0] = make_float4(mx, my, A, Bc);
                p4[1] = make_float4(D, l2a, features[g * 3 + 0], features[g * 3 + 1]);
                p4[2] = make_float4(features[g * 3 + 2], 0.f, 0.f, 0.f);
            }
        }
        __syncthreads();
    }

    flag_barrier(flagsA, goA, nblocks, MAGIC1);

    // ---------------- Phase B: segment raster -> partials ----------------
    int seglen = (N + nseg - 1) / nseg;
    for (int job = blockIdx.x; job < PB * nseg; job += nblocks) {
        int pb  = job % PB;
        int seg = job / PB;
        int g0 = seg * seglen;
        int g1 = g0 + seglen; if (g1 > N) g1 = N;
        int cnt = g1 - g0; if (cnt < 0) cnt = 0;

        int pixbase = pb * (TPB * PIXPT);
        int b = pixbase / HW;   // block pixel-span within one batch

        float4* sg4 = (float4*)smem;
        const float4* src = (const float4*)(sorted + ((size_t)b * N + g0) * 12);
        for (int i = threadIdx.x; i < cnt * 3; i += TPB) sg4[i] = src[i];
        __syncthreads();

        float px[PIXPT], py[PIXPT];
        float T[PIXPT], cr[PIXPT], cg[PIXPT], cb2[PIXPT];
        bool valid[PIXPT];
        #pragma unroll
        for (int k = 0; k < PIXPT; ++k) {
            int pix = pixbase + threadIdx.x + k * TPB;
            valid[k] = (pix < B * HW);
            int pp = valid[k] ? (pix - b * HW) : 0;
            int h = pp / W;
            int w = pp - h * W;
            px[k] = 2.0f * (float)w / (float)(W - 1) - 1.0f;
            py[k] = 2.0f * (float)h / (float)(H - 1) - 1.0f;
            T[k] = 1.0f; cr[k] = 0.f; cg[k] = 0.f; cb2[k] = 0.f;
        }

        for (int g = 0; g < cnt; ++g) {
            float4 f0 = sg4[g * 3 + 0];   // mx, my, A, Bc
            float4 f1 = sg4[g * 3 + 1];   // D, log2(alpha), r, g
            float4 f2 = sg4[g * 3 + 2];   // b, pad...
            #pragma unroll
            for (int k = 0; k < PIXPT; ++k) {
                float dx = px[k] - f0.x;
                float dy = py[k] - f0.y;
                float q = f1.y;
                q = fmaf(f1.x * dy, dy, q);
                q = fmaf(f0.w * dx, dy, q);
                q = fmaf(f0.z * dx, dx, q);
                float am = exp2f(q);
                float wgt = T[k] * am;
                cr[k]  = fmaf(wgt, f1.z, cr[k]);
                cg[k]  = fmaf(wgt, f1.w, cg[k]);
                cb2[k] = fmaf(wgt, f2.x, cb2[k]);
                T[k] = fmaf(-am, T[k], T[k]);
            }
        }

        #pragma unroll
        for (int k = 0; k < PIXPT; ++k) {
            int pix = pixbase + threadIdx.x + k * TPB;
            if (!valid[k]) continue;
            float4* o = (float4*)(partials + ((size_t)seg * (size_t)(B * HW) + pix) * 4);
            *o = make_float4(cr[k], cg[k], cb2[k], T[k]);
        }
        __syncthreads();
    }

    flag_barrier(flagsB, goB, nblocks, MAGIC2);

    // ---------------- Phase C: ordered combine -> out ----------------
    int ncomb = (B * HW + TPB - 1) / TPB;
    for (int job = blockIdx.x; job < ncomb; job += nblocks) {
        int pix = job * TPB + threadIdx.x;
        if (pix >= B * HW) continue;
        int b = pix / HW;
        int pp = pix - b * HW;
        float T = 1.0f, cr = 0.f, cg = 0.f, cb2 = 0.f;
        for (int s = 0; s < nseg; ++s) {
            float4 p = *(const float4*)(partials + ((size_t)s * (size_t)(B * HW) + pix) * 4);
            cr  = fmaf(T, p.x, cr);
            cg  = fmaf(T, p.y, cg);
            cb2 = fmaf(T, p.z, cb2);
            T *= p.w;
        }
        out[((size_t)b * 3 + 0) * HW + pp] = cr;
        out[((size_t)b * 3 + 1) * HW + pp] = cg;
        out[((size_t)b * 3 + 2) * HW + pp] = cb2;
    }
}

// ---------------------------------------------------------------------------
extern "C" void kernel_launch(void* const* d_in, const int* in_sizes, int n_in,
                              void* d_out, int out_size, void* d_ws, size_t ws_size,
                              hipStream_t stream)
{
    const float* pose      = (const float*)d_in[0];
    const float* positions = (const float*)d_in[1];
    const float* scales    = (const float*)d_in[2];
    const float* rotations = (const float*)d_in[3];
    const float* opacity   = (const float*)d_in[4];
    const float* features  = (const float*)d_in[5];
    const int*   pH        = (const int*)d_in[6];
    const int*   pW        = (const int*)d_in[7];

    int B = in_sizes[0] / 16;
    int N = in_sizes[1] / 3;
    int HW = out_size / (3 * B);

    float* out = (float*)d_out;

    // grid sizing: PB pixel-blocks x nseg segments, capped for co-residency
    int PB = (B * HW + TPB * PIXPT - 1) / (TPB * PIXPT);
    int nseg = NSEG_MAX;
    while (PB * nseg > MAXBLOCKS && nseg > 1) nseg >>= 1;
    int nblocks = PB * nseg;
    int nprep = (N + 31) >> 5;
    if (nblocks < B * nprep) nblocks = B * nprep;
    if (nblocks > MAXBLOCKS) nblocks = MAXBLOCKS;

    // workspace layout (256-byte aligned chunks; go words on their own lines)
    char* wp = (char*)d_ws;
    unsigned int* flagsA = (unsigned int*)wp;
    wp += ((size_t)nblocks * sizeof(unsigned int) + 255) & ~(size_t)255;
    unsigned int* goA = (unsigned int*)wp;
    wp += 256;
    unsigned int* flagsB = (unsigned int*)wp;
    wp += ((size_t)nblocks * sizeof(unsigned int) + 255) & ~(size_t)255;
    unsigned int* goB = (unsigned int*)wp;
    wp += 256;
    float* sorted = (float*)wp;
    wp += ((size_t)B * N * 12 * sizeof(float) + 255) & ~(size_t)255;
    float* partials = (float*)wp;

    int seglen = (N + nseg - 1) / nseg;
    size_t smem_a = (size_t)N * sizeof(unsigned long long);
    size_t smem_b = (size_t)seglen * 3 * sizeof(float4);
    size_t smem = smem_a > smem_b ? smem_a : smem_b;

    gs_fused<<<nblocks, TPB, smem, stream>>>(
        pose, positions, scales, rotations, opacity, features, pH, pW,
        flagsA, goA, flagsB, goB, sorted, partials, out,
        N, B, HW, PB, nseg, nblocks);
}

// Round 12
// 117.013 us; speedup vs baseline: 1.3356x; 1.3356x over previous
//
#include <hip/hip_runtime.h>
#include <math.h>

#define TPB 256
#define PIXPT 4          // pixels per thread in raster
#define NSEG_MAX 32

// ---------------------------------------------------------------------------
// Order-preserving float->uint map (ascending uint == ascending float).
// ---------------------------------------------------------------------------
__device__ __forceinline__ unsigned int f2ord(float f) {
    unsigned int u = __float_as_uint(f);
    return (u & 0x80000000u) ? ~u : (u | 0x80000000u);
}

// ---------------------------------------------------------------------------
// Kernel 1: fused preprocess + parallel rank, writing params directly to the
// depth-sorted slot.  Grid: (ceil(N/32), B), 256 threads.
// Phase 1: all threads cooperatively compute all N sort keys into LDS.
// Phase 2: 8 scanner lanes per gaussian count keys < own key (interleaved
//          m = s + 8*i scan -> conflict-free LDS broadcast).
// Phase 3: lane s==0 runs the full per-gaussian preprocess and writes the
//          12-float param block to sorted[rank].
// params (pre-folded): f4[0]=(mx,my,A,Bc) f4[1]=(D,log2(alpha),r,g)
//                      f4[2]=(b,0,0,0);  A,Bc,D scaled by -0.5*log2(e)
// raster: alpha_map = exp2(A dx^2 + Bc dx dy + D dy^2 + log2(alpha))
// ---------------------------------------------------------------------------
__global__ void gs_prep_rank(const float* __restrict__ pose,
                             const float* __restrict__ positions,
                             const float* __restrict__ scales,
                             const float* __restrict__ rotations,
                             const float* __restrict__ opacity,
                             const float* __restrict__ features,
                             float* __restrict__ sorted,   // B*N*12
                             int N)
{
    extern __shared__ unsigned long long skey[];   // N keys
    const int b = blockIdx.y;
    const float* P = pose + b * 16;
    const float C_EXP = -0.72134752044448170f;     // -0.5 * log2(e)

    // phase 1: keys
    for (int n = threadIdx.x; n < N; n += TPB) {
        float x = positions[n * 3 + 0];
        float y = positions[n * 3 + 1];
        float z = positions[n * 3 + 2];
        float depth = P[8] * x + P[9] * y + P[10] * z + P[11];
        skey[n] = ((unsigned long long)(~f2ord(depth)) << 32) | (unsigned int)n;
    }
    __syncthreads();

    // phase 2: rank
    int g = blockIdx.x * 32 + (threadIdx.x >> 3);
    int s = threadIdx.x & 7;
    if (g >= N) return;
    unsigned long long kn = skey[g];
    int cnt = 0;
    for (int m = s; m < N; m += 8) cnt += (skey[m] < kn) ? 1 : 0;
    cnt += __shfl_down(cnt, 4, 8);
    cnt += __shfl_down(cnt, 2, 8);
    cnt += __shfl_down(cnt, 1, 8);
    if (s != 0) return;
    int rank = cnt;

    // phase 3: preprocess gaussian g -> sorted[rank]
    float x = positions[g * 3 + 0];
    float y = positions[g * 3 + 1];
    float z = positions[g * 3 + 2];

    float depth = P[8] * x + P[9] * y + P[10] * z + P[11];
    float inv_d = 1.0f / depth;
    float mx = (P[0] * x + P[1] * y + P[2] * z + P[3]) * inv_d;
    float my = (P[4] * x + P[5] * y + P[6] * z + P[7]) * inv_d;

    float qw = rotations[g * 4 + 0];
    float qx = rotations[g * 4 + 1];
    float qy = rotations[g * 4 + 2];
    float qz = rotations[g * 4 + 3];
    float qn = sqrtf(qw * qw + qx * qx + qy * qy + qz * qz);
    qw /= qn; qx /= qn; qy /= qn; qz /= qn;
    float R00 = 1.f - 2.f * (qy * qy + qz * qz);
    float R01 = 2.f * (qx * qy - qw * qz);
    float R02 = 2.f * (qx * qz + qw * qy);
    float R10 = 2.f * (qx * qy + qw * qz);
    float R11 = 1.f - 2.f * (qx * qx + qz * qz);
    float R12 = 2.f * (qy * qz - qw * qx);
    float R20 = 2.f * (qx * qz - qw * qy);
    float R21 = 2.f * (qy * qz + qw * qx);
    float R22 = 1.f - 2.f * (qx * qx + qy * qy);

    float s0 = scales[g * 3 + 0];
    float s1 = scales[g * 3 + 1];
    float s2 = scales[g * 3 + 2];
    float v0 = s0 * s0, v1 = s1 * s1, v2 = s2 * s2;

    float C00 = R00 * R00 * v0 + R01 * R01 * v1 + R02 * R02 * v2;
    float C01 = R00 * R10 * v0 + R01 * R11 * v1 + R02 * R12 * v2;
    float C02 = R00 * R20 * v0 + R01 * R21 * v1 + R02 * R22 * v2;
    float C11 = R10 * R10 * v0 + R11 * R11 * v1 + R12 * R12 * v2;
    float C12 = R10 * R20 * v0 + R11 * R21 * v1 + R12 * R22 * v2;
    float C22 = R20 * R20 * v0 + R21 * R21 * v1 + R22 * R22 * v2;

    // Jacobian uses WORLD z and world x,y (faithful to reference)
    float fx = P[0], fy = P[5];
    float iz = 1.0f / z;
    float a0 = fx * iz;
    float c0 = -fx * x * iz * iz;
    float b1 = fy * iz;
    float c1 = -fy * y * iz * iz;

    float cov00 = a0 * a0 * C00 + 2.f * a0 * c0 * C02 + c0 * c0 * C22;
    float cov01 = a0 * b1 * C01 + a0 * c1 * C02 + c0 * b1 * C12 + c0 * c1 * C22;
    float cov11 = b1 * b1 * C11 + 2.f * b1 * c1 * C12 + c1 * c1 * C22;

    float det = cov00 * cov11 - cov01 * cov01;
    float invdet = 1.0f / det;
    float A  = C_EXP * cov11 * invdet;
    float Bc = C_EXP * -2.0f * cov01 * invdet;
    float D  = C_EXP * cov00 * invdet;
    float l2a = log2f(opacity[g]);

    float4* p4 = (float4*)(sorted + ((size_t)b * N + rank) * 12);
    p4[0] = make_float4(mx, my, A, Bc);
    p4[1] = make_float4(D, l2a, features[g * 3 + 0], features[g * 3 + 1]);
    p4[2] = make_float4(features[g * 3 + 2], 0.f, 0.f, 0.f);
}

// ---------------------------------------------------------------------------
// Kernel 2: rasterize one segment per block, PIXPT pixels per thread.
// Coalesced LDS staging from the already-sorted param array.
// ---------------------------------------------------------------------------
__global__ void gs_raster_partial(const float* __restrict__ sorted,
                                  float* __restrict__ partials,
                                  const int* __restrict__ pH,
                                  const int* __restrict__ pW,
                                  int N, int B, int HW, int nseg)
{
    extern __shared__ float4 sg4[];
    int H = *pH;
    int W = *pW;
    int seg = blockIdx.y;
    int seglen = (N + nseg - 1) / nseg;
    int g0 = seg * seglen;
    int g1 = g0 + seglen; if (g1 > N) g1 = N;
    int cnt = g1 - g0; if (cnt < 0) cnt = 0;

    int pixbase = blockIdx.x * (TPB * PIXPT);
    int b = pixbase / HW;   // block pixel-span stays within one batch here

    const float4* src = (const float4*)(sorted + ((size_t)b * N + g0) * 12);
    for (int i = threadIdx.x; i < cnt * 3; i += TPB) sg4[i] = src[i];
    __syncthreads();

    float px[PIXPT], py[PIXPT];
    float T[PIXPT], cr[PIXPT], cg[PIXPT], cb[PIXPT];
    bool valid[PIXPT];
    #pragma unroll
    for (int k = 0; k < PIXPT; ++k) {
        int pix = pixbase + threadIdx.x + k * TPB;
        valid[k] = (pix < B * HW);
        int pp = valid[k] ? (pix - b * HW) : 0;
        int h = pp / W;
        int w = pp - h * W;
        px[k] = 2.0f * (float)w / (float)(W - 1) - 1.0f;
        py[k] = 2.0f * (float)h / (float)(H - 1) - 1.0f;
        T[k] = 1.0f; cr[k] = 0.f; cg[k] = 0.f; cb[k] = 0.f;
    }

    for (int g = 0; g < cnt; ++g) {
        float4 f0 = sg4[g * 3 + 0];   // mx, my, A, Bc
        float4 f1 = sg4[g * 3 + 1];   // D, log2(alpha), r, g
        float4 f2 = sg4[g * 3 + 2];   // b, pad...
        #pragma unroll
        for (int k = 0; k < PIXPT; ++k) {
            float dx = px[k] - f0.x;
            float dy = py[k] - f0.y;
            float q = f1.y;
            q = fmaf(f1.x * dy, dy, q);
            q = fmaf(f0.w * dx, dy, q);
            q = fmaf(f0.z * dx, dx, q);
            float am = exp2f(q);
            float wgt = T[k] * am;
            cr[k] = fmaf(wgt, f1.z, cr[k]);
            cg[k] = fmaf(wgt, f1.w, cg[k]);
            cb[k] = fmaf(wgt, f2.x, cb[k]);
            T[k] = fmaf(-am, T[k], T[k]);
        }
    }

    #pragma unroll
    for (int k = 0; k < PIXPT; ++k) {
        int pix = pixbase + threadIdx.x + k * TPB;
        if (!valid[k]) continue;
        float4* o = (float4*)(partials + ((size_t)seg * (size_t)(B * HW) + pix) * 4);
        *o = make_float4(cr[k], cg[k], cb[k], T[k]);
    }
}

// ---------------------------------------------------------------------------
// Kernel 3: chain segments far-to-near and write (B,3,H,W).
// ---------------------------------------------------------------------------
__global__ void gs_combine(const float* __restrict__ partials,
                           float* __restrict__ out,
                           int B, int HW, int nseg)
{
    int pix = blockIdx.x * blockDim.x + threadIdx.x;
    if (pix >= B * HW) return;
    int b = pix / HW;
    int pp = pix - b * HW;
    float T = 1.0f, cr = 0.f, cg = 0.f, cb = 0.f;
    for (int s = 0; s < nseg; ++s) {
        float4 p = *(const float4*)(partials + ((size_t)s * (size_t)(B * HW) + pix) * 4);
        cr = fmaf(T, p.x, cr);
        cg = fmaf(T, p.y, cg);
        cb = fmaf(T, p.z, cb);
        T *= p.w;
    }
    out[((size_t)b * 3 + 0) * HW + pp] = cr;
    out[((size_t)b * 3 + 1) * HW + pp] = cg;
    out[((size_t)b * 3 + 2) * HW + pp] = cb;
}

// ---------------------------------------------------------------------------
extern "C" void kernel_launch(void* const* d_in, const int* in_sizes, int n_in,
                              void* d_out, int out_size, void* d_ws, size_t ws_size,
                              hipStream_t stream)
{
    const float* pose      = (const float*)d_in[0];
    const float* positions = (const float*)d_in[1];
    const float* scales    = (const float*)d_in[2];
    const float* rotations = (const float*)d_in[3];
    const float* opacity   = (const float*)d_in[4];
    const float* features  = (const float*)d_in[5];
    const int*   pH        = (const int*)d_in[6];
    const int*   pW        = (const int*)d_in[7];

    int B = in_sizes[0] / 16;
    int N = in_sizes[1] / 3;
    int HW = out_size / (3 * B);

    float* out = (float*)d_out;

    // workspace layout (16-byte aligned chunks)
    char* wp = (char*)d_ws;
    float* sorted = (float*)wp;
    wp += ((size_t)B * N * 12 * sizeof(float) + 15) & ~(size_t)15;
    float* partials = (float*)wp;

    size_t used = (size_t)(wp - (char*)d_ws);
    size_t avail = ws_size > used ? ws_size - used : 0;
    long long ns = (long long)(avail / ((size_t)B * HW * 4 * sizeof(float)));
    int nseg = (int)(ns > NSEG_MAX ? NSEG_MAX : ns);
    if (nseg < 1) nseg = 1;

    dim3 g1((N + 31) / 32, B);
    gs_prep_rank<<<g1, TPB, N * sizeof(unsigned long long), stream>>>(
        pose, positions, scales, rotations, opacity, features, sorted, N);

    int seglen = (N + nseg - 1) / nseg;
    dim3 g3((B * HW + TPB * PIXPT - 1) / (TPB * PIXPT), nseg);
    gs_raster_partial<<<g3, TPB, (size_t)seglen * 3 * sizeof(float4), stream>>>(
        sorted, partials, pH, pW, N, B, HW, nseg);

    gs_combine<<<(B * HW + TPB - 1) / TPB, TPB, 0, stream>>>(
        partials, out, B, HW, nseg);
}